// Round 1
// baseline (406.761 us; speedup 1.0000x reference)
//
#include <hip/hip_runtime.h>

// SelfAttention: B=2,S=2048,D=1024,H=16,E=64. Softmax over QUERY axis.
// out = concat_h( softmax_q(QK^T/8) @ V ) @ w_agg
// Strategy: bf16 MFMA (16x16x32) everywhere, fp32 accum.
//   m[t] = max_s score, l[t] = sum_s 2^(score*log2e/8 - m)  (base-2, per key col)
//   heads[s,e] = sum_t 2^(score*C1 - m[t]) * (1/l[t]) * V[t,e]
// All MFMA frag loads are 16B-contiguous along K via pre-transposed layouts.

typedef __attribute__((ext_vector_type(8))) short bf16x8;
typedef __attribute__((ext_vector_type(4))) float f32x4;

#define C1 0.18033688011112042f  // log2(e)/8

__device__ __forceinline__ unsigned short f2bf(float f){
  unsigned int u = __builtin_bit_cast(unsigned int, f);
  u = (u + 0x7FFFu + ((u >> 16) & 1u)) >> 16;  // RNE
  return (unsigned short)u;
}

__device__ __forceinline__ unsigned long long pack4bf(float a, float b, float c, float d){
  return (unsigned long long)f2bf(a)
       | ((unsigned long long)f2bf(b) << 16)
       | ((unsigned long long)f2bf(c) << 32)
       | ((unsigned long long)f2bf(d) << 48);
}

// ---------------- prep ----------------
__global__ void k_cvt_x(const float* __restrict__ in, unsigned short* __restrict__ out){
  int i = (blockIdx.x * 256 + threadIdx.x) * 4;
  float4 v = *reinterpret_cast<const float4*>(in + i);
  *reinterpret_cast<unsigned long long*>(out + i) = pack4bf(v.x, v.y, v.z, v.w);
}

// w [H][D][E] -> out [H*E][D]   (per-head transpose; K-dim d contiguous)
__global__ void k_cvt_wt(const float* __restrict__ w, unsigned short* __restrict__ out){
  int o = blockIdx.x * 256 + threadIdx.x;   // o = he*1024 + d
  int he = o >> 10, d = o & 1023;
  int h = he >> 6, e = he & 63;
  out[o] = f2bf(w[(h << 16) + (d << 6) + e]);
}

// w_agg [H*E][D] -> out [D][H*E]
__global__ void k_cvt_wagg(const float* __restrict__ w, unsigned short* __restrict__ out){
  int o = blockIdx.x * 256 + threadIdx.x;   // o = d*1024 + he
  int d = o >> 10, he = o & 1023;
  out[o] = f2bf(w[(he << 10) + d]);
}

// ---------------- projections ----------------
// D[n][m] = sum_k Wt[n][k]*Xb[m][k].  n<1024(he), m<4096(b*2048+s), K=1024.
// mode 0/1: out[m*1024+n] bf16 (Q/K rowmajor [s][he]) ; mode 2: Vt[(b*1024+n)][m-b*2048]
__global__ __launch_bounds__(256) void k_proj(const unsigned short* __restrict__ Wt,
                                              const unsigned short* __restrict__ Xb,
                                              unsigned short* __restrict__ outp,
                                              int mode){
  const int w = threadIdx.x >> 6, lane = threadIdx.x & 63;
  const int g = lane >> 4, cl = lane & 15;
  const int n0 = blockIdx.x * 128 + w * 32;
  const int m0 = blockIdx.y * 64;
  f32x4 acc[2][4];
#pragma unroll
  for (int i = 0; i < 2; ++i)
#pragma unroll
    for (int j = 0; j < 4; ++j) acc[i][j] = f32x4{0.f, 0.f, 0.f, 0.f};

  const unsigned short* wp0 = Wt + (size_t)(n0 + cl) * 1024 + g * 8;
  const unsigned short* wp1 = wp0 + 16 * 1024;
  const unsigned short* xp  = Xb + (size_t)(m0 + cl) * 1024 + g * 8;
#pragma unroll 2
  for (int kk = 0; kk < 1024; kk += 32){
    bf16x8 a0 = *(const bf16x8*)(wp0 + kk);
    bf16x8 a1 = *(const bf16x8*)(wp1 + kk);
#pragma unroll
    for (int j = 0; j < 4; ++j){
      bf16x8 b = *(const bf16x8*)(xp + (size_t)j * 16 * 1024 + kk);
      acc[0][j] = __builtin_amdgcn_mfma_f32_16x16x32_bf16(a0, b, acc[0][j], 0, 0, 0);
      acc[1][j] = __builtin_amdgcn_mfma_f32_16x16x32_bf16(a1, b, acc[1][j], 0, 0, 0);
    }
  }
  if (mode < 2){
#pragma unroll
    for (int i = 0; i < 2; ++i)
#pragma unroll
      for (int j = 0; j < 4; ++j){
        int m = m0 + 16 * j + cl;
        int n = n0 + 16 * i + 4 * g;
        *reinterpret_cast<unsigned long long*>(outp + (size_t)m * 1024 + n) =
            pack4bf(acc[i][j][0], acc[i][j][1], acc[i][j][2], acc[i][j][3]);
      }
  } else {
    int b = m0 >> 11;
    int col0 = m0 - b * 2048;
#pragma unroll
    for (int i = 0; i < 2; ++i)
#pragma unroll
      for (int j = 0; j < 4; ++j){
        int c2 = col0 + 16 * j + cl;
        int nb = b * 1024 + n0 + 16 * i + 4 * g;
#pragma unroll
        for (int jj = 0; jj < 4; ++jj)
          outp[(size_t)(nb + jj) * 2048 + c2] = f2bf(acc[i][j][jj]);
      }
  }
}

// ---------------- pass 1: per-key-column softmax stats ----------------
// swapped QK^T: D[t][s] = sum_e K[t,e]*Q[s,e]; per-lane online (m,l) over its s-subset,
// then shfl-merge over the 16 lanes sharing a t. Stores m2[t] (base-2 max) and rl[t]=1/l.
#define ONLINE(idx, val) { float x2 = (val) * C1; float dlt = x2 - m[idx];            \
    float e = exp2f(-fabsf(dlt)); bool gt = dlt > 0.f;                                 \
    l[idx] = gt ? (l[idx] * e + 1.f) : (l[idx] + e); m[idx] = gt ? x2 : m[idx]; }

__global__ __launch_bounds__(256) void k_stats(const unsigned short* __restrict__ Qb,
                                               const unsigned short* __restrict__ Kb,
                                               float* __restrict__ m2,
                                               float* __restrict__ rl){
  const int w = threadIdx.x >> 6, lane = threadIdx.x & 63;
  const int g = lane >> 4, cl = lane & 15;
  const int bh = blockIdx.y, b = bh >> 4, h = bh & 15;
  const int t0 = blockIdx.x * 128 + w * 32;   // wave covers 32 t (2 tiles)

  const unsigned short* kp = Kb + (size_t)(b * 2048 + t0 + cl) * 1024 + h * 64 + g * 8;
  bf16x8 a00 = *(const bf16x8*)(kp);
  bf16x8 a01 = *(const bf16x8*)(kp + 32);
  bf16x8 a10 = *(const bf16x8*)(kp + 16 * 1024);
  bf16x8 a11 = *(const bf16x8*)(kp + 16 * 1024 + 32);

  float m[8], l[8];
#pragma unroll
  for (int j = 0; j < 8; ++j){ m[j] = -INFINITY; l[j] = 0.f; }

  const unsigned short* qp = Qb + (size_t)(b * 2048 + cl) * 1024 + h * 64 + g * 8;
  for (int s0 = 0; s0 < 2048; s0 += 16){
    bf16x8 b0 = *(const bf16x8*)(qp + (size_t)s0 * 1024);
    bf16x8 b1 = *(const bf16x8*)(qp + (size_t)s0 * 1024 + 32);
    f32x4 z = {0.f, 0.f, 0.f, 0.f};
    f32x4 d0 = __builtin_amdgcn_mfma_f32_16x16x32_bf16(a00, b0, z, 0, 0, 0);
    d0 = __builtin_amdgcn_mfma_f32_16x16x32_bf16(a01, b1, d0, 0, 0, 0);
    f32x4 d1 = __builtin_amdgcn_mfma_f32_16x16x32_bf16(a10, b0, z, 0, 0, 0);
    d1 = __builtin_amdgcn_mfma_f32_16x16x32_bf16(a11, b1, d1, 0, 0, 0);
    ONLINE(0, d0[0]) ONLINE(1, d0[1]) ONLINE(2, d0[2]) ONLINE(3, d0[3])
    ONLINE(4, d1[0]) ONLINE(5, d1[1]) ONLINE(6, d1[2]) ONLINE(7, d1[3])
  }

#pragma unroll
  for (int tile = 0; tile < 2; ++tile){
    float mm[4], ll[4];
#pragma unroll
    for (int j = 0; j < 4; ++j){ mm[j] = m[tile * 4 + j]; ll[j] = l[tile * 4 + j]; }
#pragma unroll
    for (int off = 1; off < 16; off <<= 1){
#pragma unroll
      for (int j = 0; j < 4; ++j){
        float om = __shfl_xor(mm[j], off);
        float ol = __shfl_xor(ll[j], off);
        float mn = fmaxf(mm[j], om);
        ll[j] = ll[j] * exp2f(mm[j] - mn) + ol * exp2f(om - mn);
        mm[j] = mn;
      }
    }
    if (cl == 0){
      f32x4 mv = {mm[0], mm[1], mm[2], mm[3]};
      f32x4 lv = {1.f / ll[0], 1.f / ll[1], 1.f / ll[2], 1.f / ll[3]};
      *reinterpret_cast<f32x4*>(&m2[(size_t)bh * 2048 + t0 + tile * 16 + 4 * g]) = mv;
      *reinterpret_cast<f32x4*>(&rl[(size_t)bh * 2048 + t0 + tile * 16 + 4 * g]) = lv;
    }
  }
}

// ---------------- pass 2: P@V with precomputed stats ----------------
// wave = 64 queries. QK^T swapped (D=[t][s]) -> p=2^(x-m)*rl -> bf16 via per-wave LDS
// ([s][t], t-contiguous) -> headsT = Vt @ P  (D=[e][s], packed 8B stores).
__global__ __launch_bounds__(256) void k_attn(const unsigned short* __restrict__ Qb,
                                              const unsigned short* __restrict__ Kb,
                                              const unsigned short* __restrict__ Vt,
                                              const float* __restrict__ m2,
                                              const float* __restrict__ rl,
                                              unsigned short* __restrict__ Hd){
  __shared__ unsigned short Pl[4][64][32];
  const int w = threadIdx.x >> 6, lane = threadIdx.x & 63;
  const int g = lane >> 4, cl = lane & 15;
  const int bh = blockIdx.y, b = bh >> 4, h = bh & 15;
  const int s0 = blockIdx.x * 256 + w * 64;

  bf16x8 q[4][2];
#pragma unroll
  for (int ss = 0; ss < 4; ++ss){
    const unsigned short* qp = Qb + (size_t)(b * 2048 + s0 + ss * 16 + cl) * 1024 + h * 64 + g * 8;
    q[ss][0] = *(const bf16x8*)(qp);
    q[ss][1] = *(const bf16x8*)(qp + 32);
  }
  f32x4 acc[4][4];
#pragma unroll
  for (int i = 0; i < 4; ++i)
#pragma unroll
    for (int ss = 0; ss < 4; ++ss) acc[i][ss] = f32x4{0.f, 0.f, 0.f, 0.f};

  const unsigned short* kbase = Kb + (size_t)(b * 2048 + cl) * 1024 + h * 64 + g * 8;
  const unsigned short* vbase = Vt + (size_t)(b * 1024 + h * 64 + cl) * 2048 + g * 8;
  const float* mb = m2 + (size_t)bh * 2048 + 4 * g;
  const float* rb = rl + (size_t)bh * 2048 + 4 * g;

  for (int t0 = 0; t0 < 2048; t0 += 32){
#pragma unroll
    for (int tile = 0; tile < 2; ++tile){
      int tb = t0 + tile * 16;
      bf16x8 a0 = *(const bf16x8*)(kbase + (size_t)tb * 1024);
      bf16x8 a1 = *(const bf16x8*)(kbase + (size_t)tb * 1024 + 32);
      f32x4 mv = *(const f32x4*)(mb + tb);
      f32x4 rv = *(const f32x4*)(rb + tb);
#pragma unroll
      for (int ss = 0; ss < 4; ++ss){
        f32x4 z = {0.f, 0.f, 0.f, 0.f};
        f32x4 d = __builtin_amdgcn_mfma_f32_16x16x32_bf16(a0, q[ss][0], z, 0, 0, 0);
        d = __builtin_amdgcn_mfma_f32_16x16x32_bf16(a1, q[ss][1], d, 0, 0, 0);
        float p0 = exp2f(d[0] * C1 - mv[0]) * rv[0];
        float p1 = exp2f(d[1] * C1 - mv[1]) * rv[1];
        float p2 = exp2f(d[2] * C1 - mv[2]) * rv[2];
        float p3 = exp2f(d[3] * C1 - mv[3]) * rv[3];
        *reinterpret_cast<unsigned long long*>(&Pl[w][ss * 16 + cl][tile * 16 + 4 * g]) =
            pack4bf(p0, p1, p2, p3);
      }
    }
    bf16x8 bp[4];
#pragma unroll
    for (int ss = 0; ss < 4; ++ss)
      bp[ss] = *(const bf16x8*)(&Pl[w][ss * 16 + cl][g * 8]);
#pragma unroll
    for (int i = 0; i < 4; ++i){
      bf16x8 av = *(const bf16x8*)(vbase + (size_t)(16 * i) * 2048 + t0);
#pragma unroll
      for (int ss = 0; ss < 4; ++ss)
        acc[i][ss] = __builtin_amdgcn_mfma_f32_16x16x32_bf16(av, bp[ss], acc[i][ss], 0, 0, 0);
    }
  }
#pragma unroll
  for (int i = 0; i < 4; ++i)
#pragma unroll
    for (int ss = 0; ss < 4; ++ss){
      *reinterpret_cast<unsigned long long*>(
          Hd + (size_t)(b * 2048 + s0 + ss * 16 + cl) * 1024 + h * 64 + 16 * i + 4 * g) =
          pack4bf(acc[i][ss][0], acc[i][ss][1], acc[i][ss][2], acc[i][ss][3]);
    }
}

// ---------------- output projection ----------------
// out[m][n] = sum_k Hd[m][k]*Wa[n][k];  float4 stores.
__global__ __launch_bounds__(256) void k_agg(const unsigned short* __restrict__ Wa,
                                             const unsigned short* __restrict__ Hd,
                                             float* __restrict__ outp){
  const int w = threadIdx.x >> 6, lane = threadIdx.x & 63;
  const int g = lane >> 4, cl = lane & 15;
  const int n0 = blockIdx.x * 128 + w * 32;
  const int m0 = blockIdx.y * 64;
  f32x4 acc[2][4];
#pragma unroll
  for (int i = 0; i < 2; ++i)
#pragma unroll
    for (int j = 0; j < 4; ++j) acc[i][j] = f32x4{0.f, 0.f, 0.f, 0.f};

  const unsigned short* ap0 = Wa + (size_t)(n0 + cl) * 1024 + g * 8;
  const unsigned short* ap1 = ap0 + 16 * 1024;
  const unsigned short* bp  = Hd + (size_t)(m0 + cl) * 1024 + g * 8;
#pragma unroll 2
  for (int kk = 0; kk < 1024; kk += 32){
    bf16x8 a0 = *(const bf16x8*)(ap0 + kk);
    bf16x8 a1 = *(const bf16x8*)(ap1 + kk);
#pragma unroll
    for (int j = 0; j < 4; ++j){
      bf16x8 bb = *(const bf16x8*)(bp + (size_t)j * 16 * 1024 + kk);
      acc[0][j] = __builtin_amdgcn_mfma_f32_16x16x32_bf16(a0, bb, acc[0][j], 0, 0, 0);
      acc[1][j] = __builtin_amdgcn_mfma_f32_16x16x32_bf16(a1, bb, acc[1][j], 0, 0, 0);
    }
  }
#pragma unroll
  for (int i = 0; i < 2; ++i)
#pragma unroll
    for (int j = 0; j < 4; ++j)
      *reinterpret_cast<f32x4*>(outp + (size_t)(m0 + 16 * j + cl) * 1024 + n0 + 16 * i + 4 * g) =
          acc[i][j];
}

extern "C" void kernel_launch(void* const* d_in, const int* in_sizes, int n_in,
                              void* d_out, int out_size, void* d_ws, size_t ws_size,
                              hipStream_t stream) {
  const float* x    = (const float*)d_in[0];
  // d_in[1] = attention_mask (unused, as in reference)
  const float* wq   = (const float*)d_in[2];
  const float* wk   = (const float*)d_in[3];
  const float* wv   = (const float*)d_in[4];
  const float* wagg = (const float*)d_in[5];
  float* outp = (float*)d_out;

  char* ws = (char*)d_ws;
  unsigned short* Xb  = (unsigned short*)(ws);                 //  8 MB [4096][1024]
  unsigned short* Wqt = (unsigned short*)(ws + 8388608);       //  2 MB [he][d]
  unsigned short* Wkt = (unsigned short*)(ws + 10485760);      //  2 MB
  unsigned short* Wvt = (unsigned short*)(ws + 12582912);      //  2 MB
  unsigned short* Wat = (unsigned short*)(ws + 14680064);      //  2 MB [d][he]
  unsigned short* Qb  = (unsigned short*)(ws + 16777216);      //  8 MB [b*2048+s][he]
  unsigned short* Kb  = (unsigned short*)(ws + 25165824);      //  8 MB
  unsigned short* Vt  = (unsigned short*)(ws + 33554432);      //  8 MB [b*1024+he][s]
  unsigned short* Hd  = (unsigned short*)(ws + 41943040);      //  8 MB [b*2048+s][he]
  float* m2 = (float*)(ws + 50331648);                         // 256 KB [bh][t]
  float* rl = (float*)(ws + 50593792);                         // 256 KB
  // total 50,855,936 bytes of ws used

  k_cvt_x   <<<dim3(4096), dim3(256), 0, stream>>>(x, Xb);
  k_cvt_wt  <<<dim3(4096), dim3(256), 0, stream>>>(wq, Wqt);
  k_cvt_wt  <<<dim3(4096), dim3(256), 0, stream>>>(wk, Wkt);
  k_cvt_wt  <<<dim3(4096), dim3(256), 0, stream>>>(wv, Wvt);
  k_cvt_wagg<<<dim3(4096), dim3(256), 0, stream>>>(wagg, Wat);

  k_proj<<<dim3(8, 64), dim3(256), 0, stream>>>(Wqt, Xb, Qb, 0);
  k_proj<<<dim3(8, 64), dim3(256), 0, stream>>>(Wkt, Xb, Kb, 1);
  k_proj<<<dim3(8, 64), dim3(256), 0, stream>>>(Wvt, Xb, Vt, 2);

  k_stats<<<dim3(16, 32), dim3(256), 0, stream>>>(Qb, Kb, m2, rl);
  k_attn <<<dim3(8, 32),  dim3(256), 0, stream>>>(Qb, Kb, Vt, m2, rl, Hd);
  k_agg  <<<dim3(8, 64),  dim3(256), 0, stream>>>(Wat, Hd, outp);
}